// Round 7
// baseline (1953.607 us; speedup 1.0000x reference)
//
#include <hip/hip_runtime.h>
#include <hip/hip_bf16.h>
#include <stdint.h>

#define NN 512
#define FEAT 128
#define EMBD 64
#define HID 128

typedef float f32x4 __attribute__((ext_vector_type(4)));
typedef short s16x4 __attribute__((ext_vector_type(4)));
typedef short s16x8 __attribute__((ext_vector_type(8)));

// ---------------- Threefry-2x32 (exact JAX semantics) ----------------
__device__ __forceinline__ uint32_t rotl32(uint32_t v, int s){ return (v << s) | (v >> (32 - s)); }

__device__ __forceinline__ void tf2x32(uint32_t k0, uint32_t k1, uint32_t x0, uint32_t x1,
                                       uint32_t &o0, uint32_t &o1){
  uint32_t k2 = k0 ^ k1 ^ 0x1BD11BDAu;
  x0 += k0; x1 += k1;
  x0+=x1; x1=rotl32(x1,13); x1^=x0;
  x0+=x1; x1=rotl32(x1,15); x1^=x0;
  x0+=x1; x1=rotl32(x1,26); x1^=x0;
  x0+=x1; x1=rotl32(x1, 6); x1^=x0;
  x0 += k1; x1 += k2 + 1u;
  x0+=x1; x1=rotl32(x1,17); x1^=x0;
  x0+=x1; x1=rotl32(x1,29); x1^=x0;
  x0+=x1; x1=rotl32(x1,16); x1^=x0;
  x0+=x1; x1=rotl32(x1,24); x1^=x0;
  x0 += k2; x1 += k0 + 2u;
  x0+=x1; x1=rotl32(x1,13); x1^=x0;
  x0+=x1; x1=rotl32(x1,15); x1^=x0;
  x0+=x1; x1=rotl32(x1,26); x1^=x0;
  x0+=x1; x1=rotl32(x1, 6); x1^=x0;
  x0 += k0; x1 += k1 + 3u;
  x0+=x1; x1=rotl32(x1,17); x1^=x0;
  x0+=x1; x1=rotl32(x1,29); x1^=x0;
  x0+=x1; x1=rotl32(x1,16); x1^=x0;
  x0+=x1; x1=rotl32(x1,24); x1^=x0;
  x0 += k1; x1 += k2 + 4u;
  x0+=x1; x1=rotl32(x1,13); x1^=x0;
  x0+=x1; x1=rotl32(x1,15); x1^=x0;
  x0+=x1; x1=rotl32(x1,26); x1^=x0;
  x0+=x1; x1=rotl32(x1, 6); x1^=x0;
  x0 += k2; x1 += k0 + 5u;
  o0 = x0; o1 = x1;
}

// uniform(key,(n,),0.01,0.1) bit-exact elementwise transform
__device__ __forceinline__ float bits_to_noise(uint32_t bits){
  float u = __builtin_bit_cast(float, (bits >> 9) | 0x3f800000u) - 1.0f;
  const float dlt = 0.1f - 0.01f;
  float v = __fadd_rn(__fmul_rn(u, dlt), 0.01f); // no FMA, as XLA emits
  return fmaxf(0.01f, v);
}

__device__ __forceinline__ short f2bf(float f){
  uint32_t u = __builtin_bit_cast(uint32_t, f);
  u += 0x7fffu + ((u >> 16) & 1u);
  return (short)(u >> 16);
}

__device__ __forceinline__ float fsig(float x){
  return __builtin_amdgcn_rcpf(1.0f + __expf(-x));
}
__device__ __forceinline__ float ftanh(float x){
  float e = __expf(2.0f * x);
  return 1.0f - 2.0f * __builtin_amdgcn_rcpf(e + 1.0f);
}
__device__ __forceinline__ float softplusf(float x){
  return log1pf(expf(x));
}

// barrier that drains only LDS (lgkmcnt), letting global loads float across
__device__ __forceinline__ void lds_barrier(){
  asm volatile("s_waitcnt lgkmcnt(0)\n\ts_barrier" ::: "memory");
}

// ---------------- fast 64-lane reductions (DPP + swizzle) ----------------
__device__ __forceinline__ float wave_fmax(float x){
  int xi;
  #define DSTEP(C) xi = __builtin_amdgcn_update_dpp(0, __builtin_bit_cast(int,x), C, 0xF, 0xF, true); \
                   x = fmaxf(x, __builtin_bit_cast(float,xi));
  DSTEP(0xB1)   /* xor1  */
  DSTEP(0x4E)   /* xor2  */
  DSTEP(0x141)  /* xor4  row_half_mirror */
  DSTEP(0x140)  /* xor8  row_mirror      */
  #undef DSTEP
  xi = __builtin_amdgcn_ds_swizzle(__builtin_bit_cast(int,x), 0x401F); // xor16
  x = fmaxf(x, __builtin_bit_cast(float,xi));
  x = fmaxf(x, __shfl_xor(x, 32));
  return x;
}
__device__ __forceinline__ uint32_t wave_maxu(uint32_t x){
  int m;
  #define USTEP(C) m = __builtin_amdgcn_update_dpp(0, (int)x, C, 0xF, 0xF, true); \
                   x = x > (uint32_t)m ? x : (uint32_t)m;
  USTEP(0xB1) USTEP(0x4E) USTEP(0x141) USTEP(0x140)
  #undef USTEP
  m = __builtin_amdgcn_ds_swizzle((int)x, 0x401F);
  x = x > (uint32_t)m ? x : (uint32_t)m;
  uint32_t o = (uint32_t)__shfl_xor((int)x, 32);
  x = x > o ? x : o;
  return x;
}

// ---------------- K1: walks (16 waves/block, 4/SIMD) + featifw ----------------
// Walk selection math identical to round 3/6 (bit-identical orders).  kt is
// computed one step ahead on wave-uniform SGPRs (SALU, co-issued ~free).
__global__ __launch_bounds__(1024) void k_mega1(const float* __restrict__ adj,
    int* __restrict__ orders, const int* __restrict__ tags,
    const float* __restrict__ W_emb, const float* __restrict__ b_emb,
    const float* __restrict__ W_ih, const float* __restrict__ b_ih,
    const float* __restrict__ b_hh, float* __restrict__ IFW){
  int bid = blockIdx.x, tid = threadIdx.x;
  int wave = tid >> 6, lane = tid & 63;

  __shared__ uint32_t pcs_all[16][NN];        // 32 KB (walk blocks)
  __shared__ int tg[NN];                      // featifw blocks
  __shared__ __align__(16) float xs_all[16][2*EMBD];

  if (bid < 32){
    // ---------------- 16 independent walk waves, no barriers ----------------
    int s = bid*16 + wave;
    uint32_t* pcs = pcs_all[wave];
    int s_u = __builtin_amdgcn_readfirstlane(s);
    uint32_t ks0, ks1; tf2x32(0u, 42u, 0u, (uint32_t)s_u, ks0, ks1); // SALU
    uint32_t ktc0, ktc1; tf2x32(ks0, ks1, 0u, 0u, ktc0, ktc1);      // kt(0)

    uint32_t vis = 0;                          // bit e = visited(lane*8+e)
    if ((s >> 3) == lane) vis |= 1u << (s & 7);
    if (lane == 0) orders[(size_t)s*NN] = s;
    unsigned long long lt = (1ull << lane) - 1ull;

    const float4* r4 = (const float4*)(adj + (size_t)s*NN);
    float4 v0 = r4[lane*2], v1 = r4[lane*2+1];

    for (int t = 0; t < NN-1; ++t){
      uint32_t kt0 = ktc0, kt1 = ktc1;
      // next step's kt on SALU, overlapped with this step's VALU work
      tf2x32(ks0, ks1, 0u, (uint32_t)(t+1), ktc0, ktc1);

      float a[8] = {v0.x,v0.y,v0.z,v0.w,v1.x,v1.y,v1.z,v1.w};
      float mx = -1.f;
      #pragma unroll
      for (int e = 0; e < 8; ++e)
        mx = fmaxf(mx, ((vis >> e) & 1) ? -1.f : a[e]);
      mx = wave_fmax(mx);
      float T = mx - 0.0901f;

      int base = 0, pos[8]; uint32_t cm = 0;
      #pragma unroll
      for (int e = 0; e < 8; ++e){
        bool c = !((vis >> e) & 1) && (a[e] >= T);
        unsigned long long bal = __ballot(c);
        pos[e] = base + __popcll(bal & lt);
        base += __popcll(bal);
        if (c) cm |= 1u << e;
      }
      #pragma unroll
      for (int e = 0; e < 8; ++e)
        if ((cm >> e) & 1){
          uint32_t a23 = (uint32_t)(a[e] * 8388608.0f);     // *2^23 exact
          pcs[pos[e]] = (a23 << 9) | (uint32_t)(lane*8 + e);
        }
      int total = base;

      uint32_t bk = 0; int bi = 0x7fffffff;
      for (int b0 = 0; b0 < total; b0 += 64){
        int k = b0 + lane;
        if (k < total){
          uint32_t pc = pcs[k];
          int idx = (int)(pc & 511u);
          uint32_t x0, x1;
          tf2x32(kt0, kt1, 0u, (uint32_t)idx, x0, x1);
          float nz = bits_to_noise(x0 ^ x1);
          uint32_t n30 = (uint32_t)(nz * 1073741824.0f);    // *2^30 exact
          uint32_t key = ((pc >> 9) << 7) + n30;
          if (key > bk || (key == bk && idx < bi)){ bk = key; bi = idx; }
        }
      }
      uint32_t km = wave_maxu(bk);
      unsigned long long msk = __ballot(bk == km);
      int widx;
      if (__popcll(msk) == 1){
        widx = __shfl(bi, __ffsll((long long)msk) - 1);
      } else {                                // rare exact-tie path
        int iv = (bk == km) ? bi : 0x7fffffff;
        #pragma unroll
        for (int off = 1; off < 64; off <<= 1){
          int o = __shfl_xor(iv, off);
          iv = o < iv ? o : iv;
        }
        widx = iv;
      }
      const float4* nr = (const float4*)(adj + (size_t)widx*NN);
      v0 = nr[lane*2]; v1 = nr[lane*2+1];
      if ((widx >> 3) == lane) vis |= 1u << (widx & 7);
      if (lane == 0) orders[(size_t)s*NN + t + 1] = widx;
    }
  } else {
    // ---------------- featifw: 16 per-wave node groups ----------------
    for (int i = tid; i < NN; i += 1024) tg[i] = tags[i];
    __syncthreads();
    int n = (bid - 32)*16 + wave;
    float* xs = xs_all[wave];
    float nf = W_emb[tg[n]*EMBD + lane] + b_emb[lane];
    float ac = 0.f;
    const float* row = adj + (size_t)n*NN;
    for (int m = 0; m < NN; ++m){
      if (row[m] > 0.5f) ac += W_emb[tg[m]*EMBD + lane];
    }
    xs[lane]        = nf;
    xs[EMBD + lane] = ac + b_emb[lane];       // same-wave LDS RAW: ordered
    const float4* xs4 = (const float4*)xs;
    for (int it = 0; it < 8; ++it){
      int g = it*64 + lane;                   // gate-major index q*128+u
      const float4* wr4 = (const float4*)(W_ih + (size_t)g*(2*EMBD));
      float a2 = b_ih[g] + b_hh[g];
      #pragma unroll 8
      for (int kk = 0; kk < 32; ++kk){
        float4 wv = wr4[kk], xv = xs4[kk];
        a2 += wv.x*xv.x + wv.y*xv.y + wv.z*xv.z + wv.w*xv.w;
      }
      IFW[(size_t)n*(4*HID) + (g & 127)*4 + (g >> 7)] = a2;  // [n][u][q]
    }
  }
}

// ---------------- K2: LSTM 32 blocks x 16 seqs, swapped MFMA, 1 barrier/step ----
// gates^T = W_hh @ h^T : A-frag = W rows (static regs), B-frag = h from LDS
// (read pattern identical to previous A-frag).  C layout col=l&15=seq,
// row=(l>>4)*4+r=unit-within-tile -> every lane owns 4 (seq,unit) pairs:
// epilogue is fully distributed, no gate redistribution, no second barrier.
// hbuf double-buffered so one lgkm-only barrier per step suffices.
__global__ __launch_bounds__(512, 1) void k_lstm(const float* __restrict__ W_hh,
    const float* __restrict__ IFW2, const int* __restrict__ orders,
    const float* __restrict__ W1s, const float* __restrict__ b1s,
    const float* __restrict__ W2s, const float* __restrict__ b2s,
    float* __restrict__ logits){
  int wg = blockIdx.x, tid = threadIdx.x;      // seqs 16*wg .. 16*wg+15
  int w = tid >> 6, l = tid & 63, l15 = l & 15, l4 = l >> 4;

  __shared__ int ord_s[NN*16];                      // [t][m], 32 KB
  __shared__ __align__(16) short hbuf[2][16][HID+8];// 8.5 KB dbuf
  __shared__ float part[4][2];

  for (int i = tid; i < NN*16; i += 512){
    int t = i >> 4, m = i & 15;
    ord_s[i] = orders[(size_t)(16*wg + m)*NN + t];
  }
  for (int i = tid; i < 2*16*(HID+8); i += 512)
    ((short*)hbuf)[i] = 0;

  // W_hh -> bf16 A-fragments; wave w owns units w*16..w*16+15
  s16x8 Wf[4][4];
  #pragma unroll
  for (int q = 0; q < 4; ++q)
    #pragma unroll
    for (int kt = 0; kt < 4; ++kt){
      int g = q*HID + w*16 + l15;
      const float* src = W_hh + (size_t)g*HID + kt*32 + l4*8;
      s16x8 v;
      #pragma unroll
      for (int e = 0; e < 8; ++e) v[e] = f2bf(src[e]);
      Wf[q][kt] = v;
    }
  __syncthreads();

  int ubase = w*16 + l4*4;                     // this lane's 4 units
  float c[4] = {0,0,0,0}, emb[4] = {0,0,0,0};

  // preload IFW gate-quads for t=0: vif[r] = IFW2[ord(seq=l15,0)][ubase+r][0..3]
  f32x4 vif[4], vifn[4];
  {
    int ord = ord_s[l15];
    const float* base = IFW2 + (size_t)ord*(4*HID) + ubase*4;
    #pragma unroll
    for (int r = 0; r < 4; ++r) vif[r] = *(const f32x4*)(base + r*4);
  }

  for (int t = 0; t < NN; ++t){
    int pb = t & 1, wb = 1 - pb;

    // prefetch next step's IFW quads (in flight across the barrier)
    int tn = (t + 1 < NN) ? t + 1 : NN - 1;
    {
      int ord = ord_s[tn*16 + l15];
      const float* base = IFW2 + (size_t)ord*(4*HID) + ubase*4;
      #pragma unroll
      for (int r = 0; r < 4; ++r) vifn[r] = *(const f32x4*)(base + r*4);
    }

    // B-fragment: h_{t-1}, lane holds h[seq=l15][k=kt*32+l4*8 ..+8]
    s16x8 Hf[4];
    #pragma unroll
    for (int kt = 0; kt < 4; ++kt)
      Hf[kt] = *(const s16x8*)&hbuf[pb][l15][kt*32 + l4*8];

    f32x4 acc[4];
    #pragma unroll
    for (int q = 0; q < 4; ++q){
      f32x4 a = {0.f, 0.f, 0.f, 0.f};
      #pragma unroll
      for (int kt = 0; kt < 4; ++kt)
        a = __builtin_amdgcn_mfma_f32_16x16x32_bf16(Wf[q][kt], Hf[kt], a, 0, 0, 0);
      acc[q] = a;
    }

    // epilogue: 4 h per lane (seq=l15, units ubase..ubase+3)
    s16x4 hp;
    #pragma unroll
    for (int r = 0; r < 4; ++r){
      float gi = acc[0][r] + vif[r][0];
      float gf = acc[1][r] + vif[r][1];
      float gg = acc[2][r] + vif[r][2];
      float go = acc[3][r] + vif[r][3];
      float si = fsig(gi), sf = fsig(gf), so = fsig(go);
      float tg = ftanh(gg);
      float cn = sf * c[r] + si * tg;
      c[r] = cn;
      float h = so * ftanh(cn);
      emb[r] += h;
      hp[r] = f2bf(h);
    }
    *(s16x4*)&hbuf[wb][l15][ubase] = hp;       // one ds_write_b64
    #pragma unroll
    for (int r = 0; r < 4; ++r) vif[r] = vifn[r];
    lds_barrier();
  }

  // ---- fused MLP heads over this block's 16 nodes ----
  float* eL = (float*)ord_s;                   // reuse 8 KB as [16][HID]
  __syncthreads();                             // ord_s no longer needed
  {
    f32x4 ev = {emb[0]*(1.0f/512.0f), emb[1]*(1.0f/512.0f),
                emb[2]*(1.0f/512.0f), emb[3]*(1.0f/512.0f)};
    *(f32x4*)&eL[l15*HID + ubase] = ev;
  }
  __syncthreads();

  int hk = tid >> 7;          // head 0..3
  int uu = tid & 127;         // hidden unit
  float b1v = b1s[hk*HID + uu];
  float w2v = W2s[hk*HID + uu];
  const float* wcol = W1s + (size_t)hk*HID*HID + uu;
  for (int m = 0; m < 16; ++m){
    const float4* es4 = (const float4*)(eL + m*HID);
    float pre = b1v;
    #pragma unroll 4
    for (int d4 = 0; d4 < 32; ++d4){
      float4 e4 = es4[d4];
      pre += e4.x * wcol[(4*d4+0)*HID];
      pre += e4.y * wcol[(4*d4+1)*HID];
      pre += e4.z * wcol[(4*d4+2)*HID];
      pre += e4.w * wcol[(4*d4+3)*HID];
    }
    float v = fmaxf(pre, 0.f) * w2v;
    #pragma unroll
    for (int off = 1; off < 64; off <<= 1) v += __shfl_xor(v, off);
    if (l == 0) part[hk][(tid >> 6) & 1] = v;
    __syncthreads();
    if (tid < 4) logits[tid*NN + 16*wg + m] = part[tid][0] + part[tid][1] + b2s[tid];
    __syncthreads();
  }
}

// ---------------- K3: BCE loss + softplus-weighted mixture ----------------
__global__ __launch_bounds__(512) void k_final(const float* __restrict__ logits,
                                               const int* __restrict__ label,
                                               const float* __restrict__ var_raw,
                                               float* __restrict__ out){
  int n = threadIdx.x;
  float lab = (float)label[0];
  float sp[4]; float tot = 0.f;
  #pragma unroll
  for (int k = 0; k < 4; ++k){ sp[k] = softplusf(var_raw[k]); tot += sp[k]; }
  float y = 0.f, bce = 0.f;
  #pragma unroll
  for (int k = 0; k < 4; ++k){
    float x = logits[k*NN + n];
    float yk = 1.0f / (1.0f + expf(-x));
    y += (sp[k] / tot) * yk;
    bce += lab * softplusf(-x) + (1.0f - lab) * softplusf(x);
  }
  out[1 + n] = y;
  __shared__ float pr[8];
  #pragma unroll
  for (int off = 1; off < 64; off <<= 1) bce += __shfl_xor(bce, off);
  if ((n & 63) == 0) pr[n >> 6] = bce;
  __syncthreads();
  if (n == 0){
    float ssum = 0.f;
    for (int i = 0; i < 8; ++i) ssum += pr[i];
    out[0] = ssum * (1.0f/512.0f);
  }
}

// ---------------- launcher ----------------
extern "C" void kernel_launch(void* const* d_in, const int* in_sizes, int n_in,
                              void* d_out, int out_size, void* d_ws, size_t ws_size,
                              hipStream_t stream) {
  const int*   node_tags = (const int*)  d_in[0];
  const float* adj       = (const float*)d_in[1];
  const int*   label     = (const int*)  d_in[2];
  const float* W_emb     = (const float*)d_in[3];
  const float* b_emb     = (const float*)d_in[4];
  const float* W_ih      = (const float*)d_in[5];
  const float* W_hh      = (const float*)d_in[6];
  const float* b_ih      = (const float*)d_in[7];
  const float* b_hh      = (const float*)d_in[8];
  const float* W1s       = (const float*)d_in[9];
  const float* b1s       = (const float*)d_in[10];
  const float* W2s       = (const float*)d_in[11];
  const float* b2s       = (const float*)d_in[12];
  const float* var_raw   = (const float*)d_in[13];
  float* out = (float*)d_out;

  float* ws     = (float*)d_ws;
  float* IFW    = ws + 65536;              // 512*512 (gate-interleaved [n][u][q])
  float* logits = IFW + 262144 + 65536;    // 4*512
  int*   orders = (int*)(logits + 2048);   // 512*512 int32

  k_mega1<<<dim3(64),  dim3(1024), 0, stream>>>(adj, orders, node_tags, W_emb,
                                                b_emb, W_ih, b_ih, b_hh, IFW);
  k_lstm <<<dim3(32),  dim3(512),  0, stream>>>(W_hh, IFW, orders, W1s, b1s,
                                                W2s, b2s, logits);
  k_final<<<dim3(1),   dim3(512),  0, stream>>>(logits, label, var_raw, out);
}

// Round 8
// 1090.171 us; speedup vs baseline: 1.7920x; 1.7920x over previous
//
#include <hip/hip_runtime.h>
#include <hip/hip_bf16.h>
#include <stdint.h>

#define NN 512
#define FEAT 128
#define EMBD 64
#define HID 128

typedef float f32x4 __attribute__((ext_vector_type(4)));
typedef short s16x4 __attribute__((ext_vector_type(4)));
typedef short s16x8 __attribute__((ext_vector_type(8)));

// ---------------- Threefry-2x32 (exact JAX semantics) ----------------
__device__ __forceinline__ uint32_t rotl32(uint32_t v, int s){ return (v << s) | (v >> (32 - s)); }

__device__ __forceinline__ void tf2x32(uint32_t k0, uint32_t k1, uint32_t x0, uint32_t x1,
                                       uint32_t &o0, uint32_t &o1){
  uint32_t k2 = k0 ^ k1 ^ 0x1BD11BDAu;
  x0 += k0; x1 += k1;
  x0+=x1; x1=rotl32(x1,13); x1^=x0;
  x0+=x1; x1=rotl32(x1,15); x1^=x0;
  x0+=x1; x1=rotl32(x1,26); x1^=x0;
  x0+=x1; x1=rotl32(x1, 6); x1^=x0;
  x0 += k1; x1 += k2 + 1u;
  x0+=x1; x1=rotl32(x1,17); x1^=x0;
  x0+=x1; x1=rotl32(x1,29); x1^=x0;
  x0+=x1; x1=rotl32(x1,16); x1^=x0;
  x0+=x1; x1=rotl32(x1,24); x1^=x0;
  x0 += k2; x1 += k0 + 2u;
  x0+=x1; x1=rotl32(x1,13); x1^=x0;
  x0+=x1; x1=rotl32(x1,15); x1^=x0;
  x0+=x1; x1=rotl32(x1,26); x1^=x0;
  x0+=x1; x1=rotl32(x1, 6); x1^=x0;
  x0 += k0; x1 += k1 + 3u;
  x0+=x1; x1=rotl32(x1,17); x1^=x0;
  x0+=x1; x1=rotl32(x1,29); x1^=x0;
  x0+=x1; x1=rotl32(x1,16); x1^=x0;
  x0+=x1; x1=rotl32(x1,24); x1^=x0;
  x0 += k1; x1 += k2 + 4u;
  x0+=x1; x1=rotl32(x1,13); x1^=x0;
  x0+=x1; x1=rotl32(x1,15); x1^=x0;
  x0+=x1; x1=rotl32(x1,26); x1^=x0;
  x0+=x1; x1=rotl32(x1, 6); x1^=x0;
  x0 += k2; x1 += k0 + 5u;
  o0 = x0; o1 = x1;
}

// uniform(key,(n,),0.01,0.1) bit-exact elementwise transform
__device__ __forceinline__ float bits_to_noise(uint32_t bits){
  float u = __builtin_bit_cast(float, (bits >> 9) | 0x3f800000u) - 1.0f;
  const float dlt = 0.1f - 0.01f;
  float v = __fadd_rn(__fmul_rn(u, dlt), 0.01f); // no FMA, as XLA emits
  return fmaxf(0.01f, v);
}

__device__ __forceinline__ short f2bf(float f){
  uint32_t u = __builtin_bit_cast(uint32_t, f);
  u += 0x7fffu + ((u >> 16) & 1u);
  return (short)(u >> 16);
}

__device__ __forceinline__ float fsig(float x){
  return __builtin_amdgcn_rcpf(1.0f + __expf(-x));
}
__device__ __forceinline__ float ftanh(float x){
  float e = __expf(2.0f * x);
  return 1.0f - 2.0f * __builtin_amdgcn_rcpf(e + 1.0f);
}
__device__ __forceinline__ float softplusf(float x){
  return log1pf(expf(x));
}

// barrier that drains only LDS (lgkmcnt), letting global loads float across
__device__ __forceinline__ void lds_barrier(){
  asm volatile("s_waitcnt lgkmcnt(0)\n\ts_barrier" ::: "memory");
}

// ---------------- fast 64-lane reductions (DPP + swizzle) ----------------
__device__ __forceinline__ float wave_fmax(float x){
  int xi;
  #define DSTEP(C) xi = __builtin_amdgcn_update_dpp(0, __builtin_bit_cast(int,x), C, 0xF, 0xF, true); \
                   x = fmaxf(x, __builtin_bit_cast(float,xi));
  DSTEP(0xB1)   /* xor1  */
  DSTEP(0x4E)   /* xor2  */
  DSTEP(0x141)  /* xor4  row_half_mirror */
  DSTEP(0x140)  /* xor8  row_mirror      */
  #undef DSTEP
  xi = __builtin_amdgcn_ds_swizzle(__builtin_bit_cast(int,x), 0x401F); // xor16
  x = fmaxf(x, __builtin_bit_cast(float,xi));
  x = fmaxf(x, __shfl_xor(x, 32));
  return x;
}
__device__ __forceinline__ uint32_t wave_maxu(uint32_t x){
  int m;
  #define USTEP(C) m = __builtin_amdgcn_update_dpp(0, (int)x, C, 0xF, 0xF, true); \
                   x = x > (uint32_t)m ? x : (uint32_t)m;
  USTEP(0xB1) USTEP(0x4E) USTEP(0x141) USTEP(0x140)
  #undef USTEP
  m = __builtin_amdgcn_ds_swizzle((int)x, 0x401F);
  x = x > (uint32_t)m ? x : (uint32_t)m;
  uint32_t o = (uint32_t)__shfl_xor((int)x, 32);
  x = x > o ? x : o;
  return x;
}

// ---------------- mega-kernel body A: greedy noisy random-walk ----------------
// (exact round-5 code: bit-identical orders, measured ~541 us)
__device__ __forceinline__ void orders_body(const float* __restrict__ adj,
                                            int* __restrict__ orders, int s){
  int lane = threadIdx.x;
  __shared__ uint32_t kts[2*(NN-1)];
  __shared__ float ca[NN];
  __shared__ int   ci[NN];

  uint32_t ks0, ks1; tf2x32(0u, 42u, 0u, (uint32_t)s, ks0, ks1);
  for (int t = lane; t < NN-1; t += 64){
    uint32_t a, b; tf2x32(ks0, ks1, 0u, (uint32_t)t, a, b);
    kts[2*t] = a; kts[2*t+1] = b;
  }
  __syncthreads();

  uint32_t vis = 0;                       // bit e = visited(lane*8+e)
  if ((s >> 3) == lane) vis |= 1u << (s & 7);
  int cur = s;
  if (lane == 0) orders[(size_t)s*NN] = s;
  unsigned long long lt = (1ull << lane) - 1ull;

  for (int t = 0; t < NN-1; ++t){
    uint32_t kt0 = kts[2*t], kt1 = kts[2*t+1];
    const float4* r4 = (const float4*)(adj + (size_t)cur*NN);
    float4 v0 = r4[lane*2], v1 = r4[lane*2+1];
    float a[8] = {v0.x,v0.y,v0.z,v0.w,v1.x,v1.y,v1.z,v1.w};

    float mx = -1.f;
    #pragma unroll
    for (int e = 0; e < 8; ++e)
      mx = fmaxf(mx, ((vis >> e) & 1) ? -1.f : a[e]);
    mx = wave_fmax(mx);
    float T = mx - 0.0901f;

    int base = 0, pos[8]; uint32_t cm = 0;
    #pragma unroll
    for (int e = 0; e < 8; ++e){
      bool c = !((vis >> e) & 1) && (a[e] >= T);
      unsigned long long bal = __ballot(c);
      pos[e] = base + __popcll(bal & lt);
      base += __popcll(bal);
      if (c) cm |= 1u << e;
    }
    #pragma unroll
    for (int e = 0; e < 8; ++e)
      if ((cm >> e) & 1){ ca[pos[e]] = a[e]; ci[pos[e]] = lane*8 + e; }
    int total = base;

    uint32_t bk = 0; int bi = 0x7fffffff;
    for (int b0 = 0; b0 < total; b0 += 64){
      int k = b0 + lane;
      if (k < total){
        int idx = ci[k]; float av = ca[k];
        uint32_t x0, x1;
        tf2x32(kt0, kt1, 0u, (uint32_t)idx, x0, x1);
        float nz = bits_to_noise(x0 ^ x1);
        uint32_t a23 = (uint32_t)(av * 8388608.0f);      // *2^23 exact
        uint32_t n30 = (uint32_t)(nz * 1073741824.0f);   // *2^30 exact
        uint32_t key = (a23 << 7) + n30;
        if (key > bk || (key == bk && idx < bi)){ bk = key; bi = idx; }
      }
    }
    uint32_t km = wave_maxu(bk);
    unsigned long long msk = __ballot(bk == km);
    int widx;
    if (__popcll(msk) == 1){
      widx = __shfl(bi, __ffsll((long long)msk) - 1);
    } else {                                // rare exact-tie path
      int iv = (bk == km) ? bi : 0x7fffffff;
      #pragma unroll
      for (int off = 1; off < 64; off <<= 1){
        int o = __shfl_xor(iv, off);
        iv = o < iv ? o : iv;
      }
      widx = iv;
    }
    cur = widx;
    if ((widx >> 3) == lane) vis |= 1u << (widx & 7);
    if (lane == 0) orders[(size_t)s*NN + t + 1] = widx;
  }
}

// ---------------- mega-kernel body B: fused input_feat + IFW ----------------
// IFW stored gate-interleaved: IFW2[n][u][q] (u=hidden unit, q=gate i/f/g/o)
__device__ __forceinline__ void featifw_body(int n, const int* __restrict__ tags,
    const float* __restrict__ adj, const float* __restrict__ W_emb,
    const float* __restrict__ b_emb, const float* __restrict__ W_ih,
    const float* __restrict__ b_ih, const float* __restrict__ b_hh,
    float* __restrict__ IFW){
  int tid = threadIdx.x;                 // = embedding dim d (0..63)
  __shared__ int tg[NN];
  __shared__ __align__(16) float xs[2*EMBD];
  for (int i = tid; i < NN; i += 64) tg[i] = tags[i];
  float nf = W_emb[tg[n]*EMBD + tid] + b_emb[tid];
  float ac = 0.f;
  for (int m = 0; m < NN; ++m){
    if (adj[(size_t)n*NN + m] > 0.5f) ac += W_emb[tg[m]*EMBD + tid];
  }
  xs[tid]        = nf;
  xs[EMBD + tid] = ac + b_emb[tid];
  __syncthreads();
  const float4* xs4 = (const float4*)xs;
  for (int it = 0; it < 8; ++it){
    int g = it*64 + tid;                 // gate-major index q*128+u
    const float4* wr4 = (const float4*)(W_ih + (size_t)g*(2*EMBD));
    float a2 = b_ih[g] + b_hh[g];
    #pragma unroll 8
    for (int kk = 0; kk < 32; ++kk){
      float4 wv = wr4[kk], xv = xs4[kk];
      a2 += wv.x*xv.x + wv.y*xv.y + wv.z*xv.z + wv.w*xv.w;
    }
    IFW[(size_t)n*(4*HID) + (g & 127)*4 + (g >> 7)] = a2;  // interleaved store
  }
}

__global__ __launch_bounds__(64) void k_mega1(const float* __restrict__ adj,
    int* __restrict__ orders, const int* __restrict__ tags,
    const float* __restrict__ W_emb, const float* __restrict__ b_emb,
    const float* __restrict__ W_ih, const float* __restrict__ b_ih,
    const float* __restrict__ b_hh, float* __restrict__ IFW){
  if (blockIdx.x < NN) orders_body(adj, orders, blockIdx.x);
  else                 featifw_body(blockIdx.x - NN, tags, adj, W_emb, b_emb,
                                    W_ih, b_ih, b_hh, IFW);
}

// ---------------- K2: LSTM, 128 blocks x 4 seqs x 4 waves ----------------
// MFMA role (per wave w): gates^T tile = W_hh-rows(A) x h^T(B); wave owns
// units w*32..w*32+31 for all 4 gates -> 32 MFMA/step.  C: col=l15=seq
// (0..3 live), row=l4*4+r = unit-in-tile.  Live lanes (l15<4) write raw
// gate sums to gl[seq][q*128+u] (8x ds_write_b128).  Barrier.  Epilogue
// role: thread (es=tid>>6, u=tid&63) computes h for (es,u) and (es,u+64):
// reads gl + prefetched IFW quad, 2 h/thread, writes bf16 h to hbuf[wb].
// Barrier.  Both barriers lgkm-only so IFW prefetch stays in flight.
__global__ __launch_bounds__(256, 1) void k_lstm(const float* __restrict__ W_hh,
    const float* __restrict__ IFW2, const int* __restrict__ orders,
    const float* __restrict__ W1s, const float* __restrict__ b1s,
    const float* __restrict__ W2s, const float* __restrict__ b2s,
    float* __restrict__ logits){
  int wg = blockIdx.x, tid = threadIdx.x;      // seqs 4*wg .. 4*wg+3
  int w = tid >> 6, l = tid & 63, l15 = l & 15, l4 = l >> 4;
  int es = tid >> 6, u = tid & 63;             // epilogue (seq, unit-low)

  __shared__ int ord_s[4*NN];                        // 8 KB [seq][t]
  __shared__ __align__(16) short hbuf[2][4][HID+8];  // 2.2 KB dbuf
  __shared__ __align__(16) float gl[4*512];          // 8 KB gates [seq][q*128+u]
  __shared__ float part[4][2];

  for (int i = tid; i < 4*NN; i += 256)
    ord_s[i] = orders[(size_t)(4*wg + (i >> 9))*NN + (i & 511)];
  for (int i = tid; i < 2*4*(HID+8); i += 256)
    ((short*)hbuf)[i] = 0;

  // W_hh -> bf16 A-fragments; wave w owns units w*32 .. w*32+31 (2 tiles)
  s16x8 Wf[4][2][4];
  #pragma unroll
  for (int q = 0; q < 4; ++q)
    #pragma unroll
    for (int j = 0; j < 2; ++j)
      #pragma unroll
      for (int kt = 0; kt < 4; ++kt){
        int g = q*HID + w*32 + j*16 + l15;
        const float* src = W_hh + (size_t)g*HID + kt*32 + l4*8;
        s16x8 v;
        #pragma unroll
        for (int e = 0; e < 8; ++e) v[e] = f2bf(src[e]);
        Wf[q][j][kt] = v;
      }
  __syncthreads();

  float c0 = 0.f, c1 = 0.f, emb0 = 0.f, emb1 = 0.f;

  // preload IFW quads for t=0  (epilogue-role indexing)
  f32x4 vifA, vifB, vifnA, vifnB;
  {
    int ord = ord_s[es*NN];
    const float* b = IFW2 + (size_t)ord*(4*HID);
    vifA = *(const f32x4*)(b + u*4);
    vifB = *(const f32x4*)(b + (u+64)*4);
  }

  for (int t = 0; t < NN; ++t){
    int pb = t & 1, wb = 1 - pb;

    // prefetch next step's IFW quads (in flight across both barriers)
    int tn = (t + 1 < NN) ? t + 1 : NN - 1;
    {
      int ord = ord_s[es*NN + tn];
      const float* b = IFW2 + (size_t)ord*(4*HID);
      vifnA = *(const f32x4*)(b + u*4);
      vifnB = *(const f32x4*)(b + (u+64)*4);
    }

    // B-frag: h_{t-1}[seq=l15&3][k slice]
    s16x8 Hf[4];
    #pragma unroll
    for (int kt = 0; kt < 4; ++kt)
      Hf[kt] = *(const s16x8*)&hbuf[pb][l15 & 3][kt*32 + l4*8];

    f32x4 acc[4][2];
    #pragma unroll
    for (int q = 0; q < 4; ++q)
      #pragma unroll
      for (int j = 0; j < 2; ++j){
        f32x4 a = {0.f, 0.f, 0.f, 0.f};
        #pragma unroll
        for (int kt = 0; kt < 4; ++kt)
          a = __builtin_amdgcn_mfma_f32_16x16x32_bf16(Wf[q][j][kt], Hf[kt], a, 0, 0, 0);
        acc[q][j] = a;
      }

    // live lanes publish raw gate sums: gl[seq][q*128 + w*32 + j*16 + l4*4 + r]
    if (l15 < 4){
      #pragma unroll
      for (int q = 0; q < 4; ++q)
        #pragma unroll
        for (int j = 0; j < 2; ++j)
          *(f32x4*)&gl[l15*512 + q*128 + w*32 + j*16 + l4*4] = acc[q][j];
    }
    lds_barrier();

    // epilogue: 2 h per thread (seq es, units u and u+64)
    {
      float gi = gl[es*512 +       u] + vifA[0];
      float gf = gl[es*512 + 128 + u] + vifA[1];
      float gg = gl[es*512 + 256 + u] + vifA[2];
      float go = gl[es*512 + 384 + u] + vifA[3];
      float cn = fsig(gf) * c0 + fsig(gi) * ftanh(gg);
      c0 = cn;
      float h = fsig(go) * ftanh(cn);
      emb0 += h;
      hbuf[wb][es][u] = f2bf(h);
    }
    {
      int u2 = u + 64;
      float gi = gl[es*512 +       u2] + vifB[0];
      float gf = gl[es*512 + 128 + u2] + vifB[1];
      float gg = gl[es*512 + 256 + u2] + vifB[2];
      float go = gl[es*512 + 384 + u2] + vifB[3];
      float cn = fsig(gf) * c1 + fsig(gi) * ftanh(gg);
      c1 = cn;
      float h = fsig(go) * ftanh(cn);
      emb1 += h;
      hbuf[wb][es][u2] = f2bf(h);
    }
    vifA = vifnA; vifB = vifnB;
    lds_barrier();
  }

  // ---- fused MLP heads over this block's 4 nodes ----
  __syncthreads();
  float* eL = gl;                               // reuse as [4][HID]
  eL[es*HID + u]      = emb0 * (1.0f/512.0f);
  eL[es*HID + u + 64] = emb1 * (1.0f/512.0f);
  __syncthreads();

  int uu = tid & 127, kk = tid >> 7;            // 2 heads in flight
  for (int k2 = 0; k2 < 2; ++k2){
    int k = kk*2 + k2;
    float b1v = b1s[k*HID + uu];
    float w2v = W2s[k*HID + uu];
    const float* wcol = W1s + (size_t)k*HID*HID + uu;
    for (int m = 0; m < 4; ++m){
      const float4* es4 = (const float4*)(eL + m*HID);
      float pre = b1v;
      #pragma unroll 4
      for (int d4 = 0; d4 < 32; ++d4){
        float4 e4 = es4[d4];
        pre += e4.x * wcol[(4*d4+0)*HID];
        pre += e4.y * wcol[(4*d4+1)*HID];
        pre += e4.z * wcol[(4*d4+2)*HID];
        pre += e4.w * wcol[(4*d4+3)*HID];
      }
      float v = fmaxf(pre, 0.f) * w2v;
      #pragma unroll
      for (int off = 1; off < 64; off <<= 1) v += __shfl_xor(v, off);
      if (l == 0) part[k][(tid >> 6) & 1] = v;
      __syncthreads();
      if (tid < 2){
        int ko = tid*2 + k2;
        logits[ko*NN + 4*wg + m] = part[ko][0] + part[ko][1] + b2s[ko];
      }
      __syncthreads();
    }
  }
}

// ---------------- K3: BCE loss + softplus-weighted mixture ----------------
__global__ __launch_bounds__(512) void k_final(const float* __restrict__ logits,
                                               const int* __restrict__ label,
                                               const float* __restrict__ var_raw,
                                               float* __restrict__ out){
  int n = threadIdx.x;
  float lab = (float)label[0];
  float sp[4]; float tot = 0.f;
  #pragma unroll
  for (int k = 0; k < 4; ++k){ sp[k] = softplusf(var_raw[k]); tot += sp[k]; }
  float y = 0.f, bce = 0.f;
  #pragma unroll
  for (int k = 0; k < 4; ++k){
    float x = logits[k*NN + n];
    float yk = 1.0f / (1.0f + expf(-x));
    y += (sp[k] / tot) * yk;
    bce += lab * softplusf(-x) + (1.0f - lab) * softplusf(x);
  }
  out[1 + n] = y;
  __shared__ float pr[8];
  #pragma unroll
  for (int off = 1; off < 64; off <<= 1) bce += __shfl_xor(bce, off);
  if ((n & 63) == 0) pr[n >> 6] = bce;
  __syncthreads();
  if (n == 0){
    float ssum = 0.f;
    for (int i = 0; i < 8; ++i) ssum += pr[i];
    out[0] = ssum * (1.0f/512.0f);
  }
}

// ---------------- launcher ----------------
extern "C" void kernel_launch(void* const* d_in, const int* in_sizes, int n_in,
                              void* d_out, int out_size, void* d_ws, size_t ws_size,
                              hipStream_t stream) {
  const int*   node_tags = (const int*)  d_in[0];
  const float* adj       = (const float*)d_in[1];
  const int*   label     = (const int*)  d_in[2];
  const float* W_emb     = (const float*)d_in[3];
  const float* b_emb     = (const float*)d_in[4];
  const float* W_ih      = (const float*)d_in[5];
  const float* W_hh      = (const float*)d_in[6];
  const float* b_ih      = (const float*)d_in[7];
  const float* b_hh      = (const float*)d_in[8];
  const float* W1s       = (const float*)d_in[9];
  const float* b1s       = (const float*)d_in[10];
  const float* W2s       = (const float*)d_in[11];
  const float* b2s       = (const float*)d_in[12];
  const float* var_raw   = (const float*)d_in[13];
  float* out = (float*)d_out;

  float* ws     = (float*)d_ws;
  float* IFW    = ws + 65536;              // 512*512 (gate-interleaved [n][u][q])
  float* logits = IFW + 262144 + 65536;    // 4*512
  int*   orders = (int*)(logits + 2048);   // 512*512 int32

  k_mega1<<<dim3(2*NN), dim3(64), 0, stream>>>(adj, orders, node_tags, W_emb,
                                               b_emb, W_ih, b_ih, b_hh, IFW);
  k_lstm <<<dim3(128), dim3(256), 0, stream>>>(W_hh, IFW, orders, W1s, b1s,
                                               W2s, b2s, logits);
  k_final<<<dim3(1),   dim3(512), 0, stream>>>(logits, label, var_raw, out);
}